// Round 4
// baseline (8278.648 us; speedup 1.0000x reference)
//
#include <hip/hip_runtime.h>

// ---------------------------------------------------------------------------
// DAG-ERC forward, MI355X. Layer-sequential v1.3.
//  - fc1 / prep / fuse / mlp: fp32 tiled GEMMs (128x128 tile, 8x8 microtile)
//  - scan: 50 blocks x 512 thr, weight-stationary in VGPRs (2 cols/thread),
//    H1-slice history in LDS, cross-block m0/m1 allgather via agent-scope
//    atomics; inter-block sync via per-block release flags + wave-parallel poll.
//  - v1.3: part[] padded to 16-float rows -> reducer uses ds_read_b128.
// Workspace: ~18.2 MB.
// ---------------------------------------------------------------------------

#define HID   300
#define NSEQ  128
#define BATCH 8
#define NLAY  4
#define EMBD  100
#define NCLS  7
#define ROWS  (BATCH*NSEQ)      // 1024
#define GS    50                // scan blocks
#define ND    6                 // dims per scan block (GS*ND == HID)
#define STH   512               // scan threads

// workspace layout (float offsets)
#define WS_H      0             // H0..H4: 5 * 307200
#define WS_GIC    1536000       // 1024*900
#define WS_GHP    2457600       // 1024*900
#define WS_WC2    3379200       // 900*600
#define WS_WP2    3919200       // 900*600
#define WS_MBUF   4459200       // 8*600
#define WS_DLOG   4464000       // 4*1024 floats
#define WS_MF     4468096       // ints: 4*128*64 (mflag)
#define WS_RF     4500864       // ints: 4*128*64 (rflag)

__device__ __forceinline__ float atom_ldf(const float* p) {
  return __hip_atomic_load((float*)p, __ATOMIC_RELAXED, __HIP_MEMORY_SCOPE_AGENT);
}
__device__ __forceinline__ void atom_stf(float* p, float v) {
  __hip_atomic_store(p, v, __ATOMIC_RELAXED, __HIP_MEMORY_SCOPE_AGENT);
}
__device__ __forceinline__ float sigm(float x) { return 1.f / (1.f + expf(-x)); }

// wave 0 polls flags[0..GS-1] in parallel (one load round-trip per poll),
// acquire-fences, then block-barriers. Producers release-store their flag.
__device__ __forceinline__ void waitflags(const int* f) {
  if (threadIdx.x < 64) {
    const int lane = threadIdx.x & 63;
    int ok = (lane >= GS) ? 1 :
             (__hip_atomic_load((int*)(f + lane), __ATOMIC_RELAXED,
                                __HIP_MEMORY_SCOPE_AGENT) != 0);
    while (!__all(ok)) {
      __builtin_amdgcn_s_sleep(1);
      ok = (lane >= GS) ? 1 :
           (__hip_atomic_load((int*)(f + lane), __ATOMIC_RELAXED,
                              __HIP_MEMORY_SCOPE_AGENT) != 0);
    }
    __builtin_amdgcn_fence(__ATOMIC_ACQUIRE, "agent");
  }
  __syncthreads();
}

// ---------------------------------------------------------------------------
// Generic fp32 GEMM body: C[M,N] = act(A[M,K] * op(B) + bias)
//  btrans=true : B is (N,K) row-major (NT);  false: B is (K,N) row-major (NN)
// ---------------------------------------------------------------------------
__device__ __forceinline__ void gemm_body(
    const float* __restrict__ A, int lda,
    const float* __restrict__ B, int ldb, bool btrans,
    const float* __restrict__ bias, bool relu,
    float* __restrict__ C, int ldc, int M, int N, int K)
{
  __shared__ __align__(16) float As[16][132];
  __shared__ __align__(16) float Bs[16][132];
  const int tid = threadIdx.x;
  const int tn = tid & 15, tm = tid >> 4;
  const int bn = blockIdx.x * 128, bm = blockIdx.y * 128;
  float acc[8][8]{};
  for (int k0 = 0; k0 < K; k0 += 16) {
    for (int idx = tid; idx < 512; idx += 256) {
      int r = idx >> 2, kc = (idx & 3) * 4;
      int gm = bm + r, gk = k0 + kc;
      float4 v{};
      if (gm < M) {
        if (gk + 3 < K) v = *(const float4*)(A + gm*lda + gk);
        else {
          const float* p = A + gm*lda + gk;
          v.x = (gk+0<K)?p[0]:0.f; v.y = (gk+1<K)?p[1]:0.f;
          v.z = (gk+2<K)?p[2]:0.f; v.w = (gk+3<K)?p[3]:0.f;
        }
      }
      As[kc+0][r]=v.x; As[kc+1][r]=v.y; As[kc+2][r]=v.z; As[kc+3][r]=v.w;
    }
    if (btrans) {
      for (int idx = tid; idx < 512; idx += 256) {
        int n = idx >> 2, kc = (idx & 3) * 4;
        int gn = bn + n, gk = k0 + kc;
        float4 v{};
        if (gn < N) {
          if (gk + 3 < K) v = *(const float4*)(B + gn*ldb + gk);
          else {
            const float* p = B + gn*ldb + gk;
            v.x = (gk+0<K)?p[0]:0.f; v.y = (gk+1<K)?p[1]:0.f;
            v.z = (gk+2<K)?p[2]:0.f; v.w = (gk+3<K)?p[3]:0.f;
          }
        }
        Bs[kc+0][n]=v.x; Bs[kc+1][n]=v.y; Bs[kc+2][n]=v.z; Bs[kc+3][n]=v.w;
      }
    } else {
      for (int idx = tid; idx < 2048; idx += 256) {
        int kk = idx >> 7, n = idx & 127;
        int gn = bn + n, gk = k0 + kk;
        Bs[kk][n] = (gn < N && gk < K) ? B[gk*ldb + gn] : 0.f;
      }
    }
    __syncthreads();
#pragma unroll
    for (int kk = 0; kk < 16; ++kk) {
      float a8[8], b8[8];
      *(float4*)&a8[0] = *(const float4*)&As[kk][tm*8];
      *(float4*)&a8[4] = *(const float4*)&As[kk][tm*8+4];
      *(float4*)&b8[0] = *(const float4*)&Bs[kk][tn*8];
      *(float4*)&b8[4] = *(const float4*)&Bs[kk][tn*8+4];
#pragma unroll
      for (int i2 = 0; i2 < 8; ++i2)
#pragma unroll
        for (int j2 = 0; j2 < 8; ++j2) acc[i2][j2] += a8[i2]*b8[j2];
    }
    __syncthreads();
  }
#pragma unroll
  for (int i2 = 0; i2 < 8; ++i2) {
    int gm = bm + tm*8 + i2;
    if (gm >= M) continue;
#pragma unroll
    for (int j2 = 0; j2 < 8; ++j2) {
      int gn = bn + tn*8 + j2;
      if (gn >= N) continue;
      float v = acc[i2][j2];
      if (bias) v += bias[gn];
      if (relu) v = fmaxf(v, 0.f);
      C[gm*ldc + gn] = v;
    }
  }
}

__global__ void k_fc1(const float* inp, const float* w, const float* b, float* H0) {
  gemm_body(inp, EMBD, w, EMBD, true, b, true, H0, HID, ROWS, HID, EMBD);
}
__global__ void k_prep(const float* Hin, const float* cwihL, const float* cbihL,
                       const float* pwhhL, const float* pbhhL, float* giC, float* ghP) {
  bool z0 = (blockIdx.z == 0);
  gemm_body(Hin, HID, z0 ? cwihL : pwhhL, HID, true, z0 ? cbihL : pbhhL, false,
            z0 ? giC : ghP, 900, ROWS, 900, HID);
}
// Wc2T = [cwhh@w0 | cwhh@w1] (900x600); Wp2T = [pwih@w0 | pwih@w1]
__global__ void k_fuse(const float* cwhhL, const float* pwihL,
                       const float* w0L, const float* w1L, float* Wc2T, float* Wp2T) {
  int z = blockIdx.z;
  const float* A  = (z < 2) ? cwhhL : pwihL;
  const float* Bm = (z & 1) ? w1L : w0L;
  float* C = ((z < 2) ? Wc2T : Wp2T) + (z & 1) * HID;
  gemm_body(A, HID, Bm, HID, false, nullptr, false, C, 600, 900, HID, HID);
}
__global__ void k_m2(const float* t1, const float* w, const float* b, float* t2) {
  gemm_body(t1, HID, w, HID, true, b, true, t2, HID, ROWS, HID, HID);
}

// mlp1: A is virtual concat [H0|H1|H2|H3|H4|inp] (1024 x 1600)
__global__ void k_mlp1(const float* __restrict__ Hcat, const float* __restrict__ inp,
                       const float* __restrict__ w, const float* __restrict__ bias,
                       float* __restrict__ out) {
  __shared__ __align__(16) float As[16][132];
  __shared__ __align__(16) float Bs[16][132];
  const int tid = threadIdx.x;
  const int tn = tid & 15, tm = tid >> 4;
  const int bn = blockIdx.x * 128, bm = blockIdx.y * 128;
  float acc[8][8]{};
  for (int k0 = 0; k0 < 1600; k0 += 16) {
    for (int idx = tid; idx < 2048; idx += 256) {
      int r = idx >> 4, kk = idx & 15;
      int gm = bm + r, gk = k0 + kk;
      float v;
      if (gk < 1500) { int seg = gk / 300; v = Hcat[seg*(ROWS*HID) + gm*HID + (gk - seg*300)]; }
      else            v = inp[gm*EMBD + (gk - 1500)];
      As[kk][r] = v;
    }
    for (int idx = tid; idx < 512; idx += 256) {
      int n = idx >> 2, kc = (idx & 3) * 4;
      int gn = bn + n, gk = k0 + kc;
      float4 v{};
      if (gn < HID) v = *(const float4*)(w + gn*1600 + gk);
      Bs[kc+0][n]=v.x; Bs[kc+1][n]=v.y; Bs[kc+2][n]=v.z; Bs[kc+3][n]=v.w;
    }
    __syncthreads();
#pragma unroll
    for (int kk = 0; kk < 16; ++kk) {
      float a8[8], b8[8];
      *(float4*)&a8[0] = *(const float4*)&As[kk][tm*8];
      *(float4*)&a8[4] = *(const float4*)&As[kk][tm*8+4];
      *(float4*)&b8[0] = *(const float4*)&Bs[kk][tn*8];
      *(float4*)&b8[4] = *(const float4*)&Bs[kk][tn*8+4];
#pragma unroll
      for (int i2 = 0; i2 < 8; ++i2)
#pragma unroll
        for (int j2 = 0; j2 < 8; ++j2) acc[i2][j2] += a8[i2]*b8[j2];
    }
    __syncthreads();
  }
#pragma unroll
  for (int i2 = 0; i2 < 8; ++i2) {
    int gm = bm + tm*8 + i2;
    if (gm >= ROWS) continue;
#pragma unroll
    for (int j2 = 0; j2 < 8; ++j2) {
      int gn = bn + tn*8 + j2;
      if (gn >= HID) continue;
      out[gm*HID + gn] = fmaxf(acc[i2][j2] + bias[gn], 0.f);
    }
  }
}

__global__ void k_mlp3(const float* __restrict__ t2, const float* __restrict__ w,
                       const float* __restrict__ b, float* __restrict__ out) {
  __shared__ float xs[32][HID];
  __shared__ float wsx[NCLS][HID];
  const int r0 = blockIdx.x * 32;
  for (int idx = threadIdx.x; idx < NCLS*HID; idx += 256) wsx[idx/HID][idx%HID] = w[idx];
  for (int idx = threadIdx.x; idx < 32*HID; idx += 256)
    xs[idx/HID][idx%HID] = t2[(r0 + idx/HID)*HID + idx%HID];
  __syncthreads();
  const int rl = threadIdx.x >> 3, o = threadIdx.x & 7;
  if (o < NCLS) {
    float acc = b[o];
    for (int k = 0; k < HID; ++k) acc += xs[rl][k]*wsx[o][k];
    out[(r0 + rl)*NCLS + o] = acc;
  }
}

// ---------------------------------------------------------------------------
// Sequential scan. 50 blocks x 512 threads; block g owns dims [g*6, g*6+6).
// Phase B thread unit: (dc2 in [0,21), ks in [0,12), bh in [0,2)) -> tid<504.
//   dc2 -> (dl=dc2/7 in [0,3), cc=dc2%7); thread owns output cols
//   dcA=dl*7+cc (dim D0+dl) and dcB=(dl+3)*7+cc (dim D0+dl+3): two 50-wide
//   weight slices in VGPRs, shares each LDS u-read across both columns.
//   Loops batches b = bh*4 .. bh*4+3.
// ---------------------------------------------------------------------------
__global__ __launch_bounds__(STH, 1)
void k_scan(const float* __restrict__ Hin, float* __restrict__ Hout,
            const float* __restrict__ giC, const float* __restrict__ ghP,
            const float* __restrict__ Wc2T, const float* __restrict__ Wp2T,
            const float* __restrict__ w0, const float* __restrict__ w1,
            const float* __restrict__ gatw,
            const float* __restrict__ cbhh, const float* __restrict__ pbih,
            const int* __restrict__ adj, const int* __restrict__ smask,
            float* __restrict__ dlog, float* __restrict__ mbuf,
            int* __restrict__ mflag, int* __restrict__ rflag)
{
  const int tid = threadIdx.x;
  const int bid = blockIdx.x;
  const int D0  = bid * ND;

  __shared__ float hist[BATCH][NSEQ][ND+1];
  __shared__ __align__(16) float uwl[BATCH][12][52];
  __shared__ __align__(16) float part[BATCH][42][16];   // 16-float rows: b128 reducer reads
  __shared__ float gate[BATCH][42];
  __shared__ float dlgl[BATCH][NSEQ];
  __shared__ float dred[BATCH][ND];

  for (int idx = tid; idx < BATCH*NSEQ*(ND+1); idx += STH) (&hist[0][0][0])[idx] = 0.f;
  for (int idx = tid; idx < BATCH*12*52;       idx += STH) (&uwl[0][0][0])[idx]  = 0.f;
  for (int idx = tid; idx < BATCH*42*16;       idx += STH) (&part[0][0][0])[idx] = 0.f;

  // ---- persistent per-thread setup -----------------------------------------
  const bool bact = (tid < 504);
  const int dc2 = tid / 24, rr = tid % 24, ks = rr >> 1, bh = rr & 1;
  const int dl = dc2 / 7, cc = dc2 % 7;
  const int dcA = dl*7 + cc, dcB = (dl+3)*7 + cc;
  float wregA[52], wregB[52];
  if (bact) {
    const int off = ks * 50;
#pragma unroll
    for (int t = 0; t < 2; ++t) {
      const int dim = D0 + dl + t*3;
      const float* src;
      if (cc < 3)      src = Wc2T + (cc*HID + dim)*600 + off;
      else if (cc < 6) src = Wp2T + ((cc-3)*HID + dim)*600 + off;
      else             src = (ks < 6) ? (w0 + dim*HID + off)
                                      : (w1 + dim*HID + off - HID);
      float* dst = t ? wregB : wregA;
#pragma unroll
      for (int q = 0; q < 50; ++q) dst[q] = src[q];
      dst[50] = 0.f; dst[51] = 0.f;
    }
  }
  const int rb = tid / 42, rdc = tid % 42;
  float rbias = 0.f;
  if (tid < 336) {
    const int rd = rdc / 7, rc = rdc % 7;
    if (rc < 3)      rbias = cbhh[rc*HID + D0 + rd];
    else if (rc < 6) rbias = pbih[(rc-3)*HID + D0 + rd];
  }
  float gw2 = 0.f;
  if (tid < BATCH*ND) gw2 = gatw[HID + D0 + (tid % ND)];

  __syncthreads();

  for (int i = 0; i < NSEQ; ++i) {
    // ---- hoisted loads (issue before any inter-block wait) -----------------
    float hx0=0,hx1=0,hx2=0,hx3=0,hx4=0,hx5=0,hx6=0;
    if (tid < BATCH*ND) {
      const int b = tid / ND, d = tid % ND, dim = D0 + d, row = b*NSEQ + i;
      const float* gi = giC + row*900;
      const float* gh = ghP + row*900;
      hx0 = gi[dim]; hx1 = gi[HID+dim]; hx2 = gi[2*HID+dim];
      hx3 = gh[dim]; hx4 = gh[HID+dim]; hx5 = gh[2*HID+dim];
      hx6 = Hin[row*HID + dim];
    }
    bool v1 = false, v2 = false; float sm1 = 0.f, sm2 = 0.f;
    if (i > 0) {
      const int b = tid >> 6, lane = tid & 63;
      const int* ar = adj   + (b*NSEQ + i)*NSEQ;
      const int* sr = smask + (b*NSEQ + i)*NSEQ;
      v1 = (lane < i)      && (ar[lane]      != 0);
      v2 = (lane + 64 < i) && (ar[lane + 64] != 0);
      sm1 = v1 ? (float)sr[lane]      : 0.f;
      sm2 = v2 ? (float)sr[lane + 64] : 0.f;
    }

    if (i > 0) {
      waitflags(rflag + (i-1)*64);
      if (tid < BATCH) dlgl[tid][i-1] = atom_ldf(dlog + tid*NSEQ + (i-1));
      __syncthreads();

      // ---- Phase A: masked softmax + m0/m1 slice (wave <-> batch) ----------
      {
        const int b = tid >> 6, lane = tid & 63;
        const float l1 = v1 ? dlgl[b][lane]      : -3.0e38f;
        const float l2 = v2 ? dlgl[b][lane + 64] : -3.0e38f;
        float mx = fmaxf(l1, l2);
#pragma unroll
        for (int off = 32; off; off >>= 1) mx = fmaxf(mx, __shfl_xor(mx, off));
        const float p1 = v1 ? expf(l1 - mx) : 0.f;
        const float p2 = v2 ? expf(l2 - mx) : 0.f;
        float ps = p1 + p2;
#pragma unroll
        for (int off = 32; off; off >>= 1) ps += __shfl_xor(ps, off);
        const float inv = 1.f / ps;     // i>=1 guarantees >=1 valid predecessor
        const float a1 = p1*inv, a2 = p2*inv;
        const float aS1 = a1*sm1, aD1 = a1 - aS1;
        const float aS2 = a2*sm2, aD2 = a2 - aS2;
        float s0[ND], s1v[ND];
#pragma unroll
        for (int d = 0; d < ND; ++d) {
          s0[d]  = aS1*hist[b][lane][d] + aS2*hist[b][lane+64][d];
          s1v[d] = aD1*hist[b][lane][d] + aD2*hist[b][lane+64][d];
        }
#pragma unroll
        for (int off = 32; off; off >>= 1) {
#pragma unroll
          for (int d = 0; d < ND; ++d) {
            s0[d]  += __shfl_xor(s0[d],  off);
            s1v[d] += __shfl_xor(s1v[d], off);
          }
        }
        if (lane == 0) {
#pragma unroll
          for (int d = 0; d < ND; ++d) {
            atom_stf(mbuf + b*600 +       D0 + d, s0[d]);
            atom_stf(mbuf + b*600 + HID + D0 + d, s1v[d]);
          }
        }
      }
      __syncthreads();   // drain mbuf stores block-wide before publishing
      if (tid == 0)
        __hip_atomic_store(mflag + i*64 + bid, 1, __ATOMIC_RELEASE, __HIP_MEMORY_SCOPE_AGENT);
      waitflags(mflag + i*64);
      for (int idx = tid; idx < BATCH*600; idx += STH) {
        const int b = idx / 600, k = idx % 600;
        uwl[b][k/50][k%50] = atom_ldf(mbuf + idx);
      }
    }
    __syncthreads();

    // ---- Phase B: fused GEMV partials, 2 columns per thread ----------------
    if (bact) {
#pragma unroll
      for (int j = 0; j < 4; ++j) {
        const int b = bh*4 + j;
        const float4* u4 = (const float4*)(&uwl[b][ks][0]);
        float accA = 0.f, accB = 0.f;
#pragma unroll
        for (int q = 0; q < 13; ++q) {
          const float4 u = u4[q];
          accA += u.x*wregA[4*q+0] + u.y*wregA[4*q+1] + u.z*wregA[4*q+2] + u.w*wregA[4*q+3];
          accB += u.x*wregB[4*q+0] + u.y*wregB[4*q+1] + u.z*wregB[4*q+2] + u.w*wregB[4*q+3];
        }
        part[b][dcA][ks] = accA;
        part[b][dcB][ks] = accB;
      }
    }
    __syncthreads();
    if (tid < 336) {
      const float4* p4 = (const float4*)(&part[rb][rdc][0]);
      const float4 q0 = p4[0], q1 = p4[1], q2 = p4[2];
      gate[rb][rdc] = rbias + ((q0.x+q0.y)+(q0.z+q0.w))
                            + ((q1.x+q1.y)+(q1.z+q1.w))
                            + ((q2.x+q2.y)+(q2.z+q2.w));
    }
    __syncthreads();

    // ---- Phase C: GRU elementwise + writeback ------------------------------
    if (tid < BATCH*ND) {
      const int b = tid / ND, d = tid % ND;
      const int dim = D0 + d, row = b*NSEQ + i;
      const float ghc_r = gate[b][d*7+0], ghc_z = gate[b][d*7+1], ghc_n = gate[b][d*7+2];
      const float gip_r = gate[b][d*7+3], gip_z = gate[b][d*7+4], gip_n = gate[b][d*7+5];
      const float Mv    = gate[b][d*7+6];             // == 0 exactly at i==0
      // C = grus_c(x, M)
      const float r  = sigm(hx0 + ghc_r);
      const float z  = sigm(hx1 + ghc_z);
      const float n  = tanhf(hx2 + r*ghc_n);
      const float Cv = (1.f - z)*n + z*Mv;
      // P = grus_p(M, x)
      const float rp = sigm(gip_r + hx3);
      const float zp = sigm(gip_z + hx4);
      const float np = tanhf(gip_n + rp*hx5);
      const float Pv = (1.f - zp)*np + zp*hx6;
      const float ov = Cv + Pv;
      Hout[row*HID + dim] = ov;
      hist[b][i][d] = ov;
      dred[b][d] = ov * gw2;
    }
    __syncthreads();
    if (tid < BATCH) {
      float s = 0.f;
#pragma unroll
      for (int d = 0; d < ND; ++d) s += dred[tid][d];
      atomicAdd(dlog + tid*NSEQ + i, s);
    }
    __syncthreads();   // drain dlog adds + Hout/hist before publishing row i
    if (tid == 0)
      __hip_atomic_store(rflag + i*64 + bid, 1, __ATOMIC_RELEASE, __HIP_MEMORY_SCOPE_AGENT);
  }
}

// ---------------------------------------------------------------------------
extern "C" void kernel_launch(void* const* d_in, const int* in_sizes, int n_in,
                              void* d_out, int out_size, void* d_ws, size_t ws_size,
                              hipStream_t stream) {
  const float* inp   = (const float*)d_in[0];
  const int*   adj   = (const int*)d_in[1];
  const int*   smask = (const int*)d_in[2];
  // d_in[3] text_length: unused by the reference forward
  const float* fc1w = (const float*)d_in[4];
  const float* fc1b = (const float*)d_in[5];
  const float* gatw = (const float*)d_in[6];
  // d_in[7] gat_b: cancels in softmax
  const float* wr0  = (const float*)d_in[8];
  const float* wr1  = (const float*)d_in[9];
  const float* cwih = (const float*)d_in[10];
  const float* cwhh = (const float*)d_in[11];
  const float* cbih = (const float*)d_in[12];
  const float* cbhh = (const float*)d_in[13];
  const float* pwih = (const float*)d_in[14];
  const float* pwhh = (const float*)d_in[15];
  const float* pbih = (const float*)d_in[16];
  const float* pbhh = (const float*)d_in[17];
  const float* m1w  = (const float*)d_in[18];
  const float* m1b  = (const float*)d_in[19];
  const float* m2w  = (const float*)d_in[20];
  const float* m2b  = (const float*)d_in[21];
  const float* m3w  = (const float*)d_in[22];
  const float* m3b  = (const float*)d_in[23];
  float* out = (float*)d_out;

  float* ws    = (float*)d_ws;
  float* H     = ws + WS_H;
  float* giC   = ws + WS_GIC;
  float* ghP   = ws + WS_GHP;
  float* Wc2T  = ws + WS_WC2;
  float* Wp2T  = ws + WS_WP2;
  float* mbuf  = ws + WS_MBUF;
  float* dlog  = ws + WS_DLOG;
  int*   mflag = (int*)(ws + WS_MF);
  int*   rflag = (int*)(ws + WS_RF);

  // zero dlog (4096 f) + mflag/rflag (2*32768 ints), contiguous: 278528 bytes
  hipMemsetAsync(dlog, 0, (size_t)(NLAY*BATCH*NSEQ)*4 + 2u*NLAY*NSEQ*64*4, stream);

  k_fc1<<<dim3(3, 8, 1), 256, 0, stream>>>(inp, fc1w, fc1b, H);

  for (int l = 0; l < NLAY; ++l) {
    float* Hin  = H + l*(ROWS*HID);
    float* Hout = H + (l+1)*(ROWS*HID);
    k_fuse<<<dim3(3, 8, 4), 256, 0, stream>>>(cwhh + l*900*HID, pwih + l*900*HID,
                                              wr0 + l*HID*HID, wr1 + l*HID*HID, Wc2T, Wp2T);
    k_prep<<<dim3(8, 8, 2), 256, 0, stream>>>(Hin, cwih + l*900*HID, cbih + l*900,
                                              pwhh + l*900*HID, pbhh + l*900, giC, ghP);
    k_scan<<<GS, STH, 0, stream>>>(Hin, Hout, giC, ghP, Wc2T, Wp2T,
                                   wr0 + l*HID*HID, wr1 + l*HID*HID, gatw + l*2*HID,
                                   cbhh + l*900, pbih + l*900,
                                   adj, smask, dlog + l*BATCH*NSEQ, mbuf,
                                   mflag + l*NSEQ*64, rflag + l*NSEQ*64);
  }

  float* t1 = giC;  // reuse
  float* t2 = ghP;
  k_mlp1<<<dim3(3, 8, 1), 256, 0, stream>>>(H, inp, m1w, m1b, t1);
  k_m2  <<<dim3(3, 8, 1), 256, 0, stream>>>(t1, m2w, m2b, t2);
  k_mlp3<<<32, 256, 0, stream>>>(t2, m3w, m3b, out);
}

// Round 5
// 7406.568 us; speedup vs baseline: 1.1177x; 1.1177x over previous
//
#include <hip/hip_runtime.h>

// ---------------------------------------------------------------------------
// DAG-ERC forward, MI355X. Layer-sequential v2.
//  v2 changes (post first real profile, dur 8278us, scan ~2ms each):
//   - Sync protocol: ALL relaxed atomics (LLC-routed). No acquire fences /
//     release stores -> no per-step L2 invalidate/writeback (was ~4 cache
//     maintenance ops x 512 steps = dominant cost; VALUBusy was 4%).
//     Ordering: __syncthreads() drains vmcnt(0) (stores ack'd at LLC) before
//     the flag store; consumers poll flag then read LLC-routed atomics.
//   - Phase-B weight loads made unconditional (all 512 thr) to remove the
//     divergent init that caused the compiler to sink/spill wregA/wregB
//     (VGPR_Count was 92 < 104 weight floats).
// Workspace: ~18.2 MB.
// ---------------------------------------------------------------------------

#define HID   300
#define NSEQ  128
#define BATCH 8
#define NLAY  4
#define EMBD  100
#define NCLS  7
#define ROWS  (BATCH*NSEQ)      // 1024
#define GS    50                // scan blocks
#define ND    6                 // dims per scan block (GS*ND == HID)
#define STH   512               // scan threads

// workspace layout (float offsets)
#define WS_H      0             // H0..H4: 5 * 307200
#define WS_GIC    1536000       // 1024*900
#define WS_GHP    2457600       // 1024*900
#define WS_WC2    3379200       // 900*600
#define WS_WP2    3919200       // 900*600
#define WS_MBUF   4459200       // 8*600
#define WS_DLOG   4464000       // 4*1024 floats
#define WS_MF     4468096       // ints: 4*128*64 (mflag)
#define WS_RF     4500864       // ints: 4*128*64 (rflag)

__device__ __forceinline__ float atom_ldf(const float* p) {
  return __hip_atomic_load((float*)p, __ATOMIC_RELAXED, __HIP_MEMORY_SCOPE_AGENT);
}
__device__ __forceinline__ void atom_stf(float* p, float v) {
  __hip_atomic_store(p, v, __ATOMIC_RELAXED, __HIP_MEMORY_SCOPE_AGENT);
}
__device__ __forceinline__ float sigm(float x) { return 1.f / (1.f + expf(-x)); }

// wave 0 polls flags[0..GS-1] in parallel; compiler barrier (no cache ops),
// then block barrier. Producers: __syncthreads (vmcnt drain) -> relaxed store.
__device__ __forceinline__ void waitflags(const int* f) {
  if (threadIdx.x < 64) {
    const int lane = threadIdx.x & 63;
    int ok = (lane >= GS) ? 1 :
             (__hip_atomic_load((int*)(f + lane), __ATOMIC_RELAXED,
                                __HIP_MEMORY_SCOPE_AGENT) != 0);
    while (!__all(ok)) {
      __builtin_amdgcn_s_sleep(1);
      ok = (lane >= GS) ? 1 :
           (__hip_atomic_load((int*)(f + lane), __ATOMIC_RELAXED,
                              __HIP_MEMORY_SCOPE_AGENT) != 0);
    }
    asm volatile("" ::: "memory");   // compiler-only ordering; data is LLC-routed
  }
  __syncthreads();
}
__device__ __forceinline__ void setflag(int* p) {
  asm volatile("" ::: "memory");
  __hip_atomic_store(p, 1, __ATOMIC_RELAXED, __HIP_MEMORY_SCOPE_AGENT);
}

// ---------------------------------------------------------------------------
// Generic fp32 GEMM body: C[M,N] = act(A[M,K] * op(B) + bias)
//  btrans=true : B is (N,K) row-major (NT);  false: B is (K,N) row-major (NN)
// ---------------------------------------------------------------------------
__device__ __forceinline__ void gemm_body(
    const float* __restrict__ A, int lda,
    const float* __restrict__ B, int ldb, bool btrans,
    const float* __restrict__ bias, bool relu,
    float* __restrict__ C, int ldc, int M, int N, int K)
{
  __shared__ __align__(16) float As[16][132];
  __shared__ __align__(16) float Bs[16][132];
  const int tid = threadIdx.x;
  const int tn = tid & 15, tm = tid >> 4;
  const int bn = blockIdx.x * 128, bm = blockIdx.y * 128;
  float acc[8][8]{};
  for (int k0 = 0; k0 < K; k0 += 16) {
    for (int idx = tid; idx < 512; idx += 256) {
      int r = idx >> 2, kc = (idx & 3) * 4;
      int gm = bm + r, gk = k0 + kc;
      float4 v{};
      if (gm < M) {
        if (gk + 3 < K) v = *(const float4*)(A + gm*lda + gk);
        else {
          const float* p = A + gm*lda + gk;
          v.x = (gk+0<K)?p[0]:0.f; v.y = (gk+1<K)?p[1]:0.f;
          v.z = (gk+2<K)?p[2]:0.f; v.w = (gk+3<K)?p[3]:0.f;
        }
      }
      As[kc+0][r]=v.x; As[kc+1][r]=v.y; As[kc+2][r]=v.z; As[kc+3][r]=v.w;
    }
    if (btrans) {
      for (int idx = tid; idx < 512; idx += 256) {
        int n = idx >> 2, kc = (idx & 3) * 4;
        int gn = bn + n, gk = k0 + kc;
        float4 v{};
        if (gn < N) {
          if (gk + 3 < K) v = *(const float4*)(B + gn*ldb + gk);
          else {
            const float* p = B + gn*ldb + gk;
            v.x = (gk+0<K)?p[0]:0.f; v.y = (gk+1<K)?p[1]:0.f;
            v.z = (gk+2<K)?p[2]:0.f; v.w = (gk+3<K)?p[3]:0.f;
          }
        }
        Bs[kc+0][n]=v.x; Bs[kc+1][n]=v.y; Bs[kc+2][n]=v.z; Bs[kc+3][n]=v.w;
      }
    } else {
      for (int idx = tid; idx < 2048; idx += 256) {
        int kk = idx >> 7, n = idx & 127;
        int gn = bn + n, gk = k0 + kk;
        Bs[kk][n] = (gn < N && gk < K) ? B[gk*ldb + gn] : 0.f;
      }
    }
    __syncthreads();
#pragma unroll
    for (int kk = 0; kk < 16; ++kk) {
      float a8[8], b8[8];
      *(float4*)&a8[0] = *(const float4*)&As[kk][tm*8];
      *(float4*)&a8[4] = *(const float4*)&As[kk][tm*8+4];
      *(float4*)&b8[0] = *(const float4*)&Bs[kk][tn*8];
      *(float4*)&b8[4] = *(const float4*)&Bs[kk][tn*8+4];
#pragma unroll
      for (int i2 = 0; i2 < 8; ++i2)
#pragma unroll
        for (int j2 = 0; j2 < 8; ++j2) acc[i2][j2] += a8[i2]*b8[j2];
    }
    __syncthreads();
  }
#pragma unroll
  for (int i2 = 0; i2 < 8; ++i2) {
    int gm = bm + tm*8 + i2;
    if (gm >= M) continue;
#pragma unroll
    for (int j2 = 0; j2 < 8; ++j2) {
      int gn = bn + tn*8 + j2;
      if (gn >= N) continue;
      float v = acc[i2][j2];
      if (bias) v += bias[gn];
      if (relu) v = fmaxf(v, 0.f);
      C[gm*ldc + gn] = v;
    }
  }
}

__global__ void k_fc1(const float* inp, const float* w, const float* b, float* H0) {
  gemm_body(inp, EMBD, w, EMBD, true, b, true, H0, HID, ROWS, HID, EMBD);
}
__global__ void k_prep(const float* Hin, const float* cwihL, const float* cbihL,
                       const float* pwhhL, const float* pbhhL, float* giC, float* ghP) {
  bool z0 = (blockIdx.z == 0);
  gemm_body(Hin, HID, z0 ? cwihL : pwhhL, HID, true, z0 ? cbihL : pbhhL, false,
            z0 ? giC : ghP, 900, ROWS, 900, HID);
}
// Wc2T = [cwhh@w0 | cwhh@w1] (900x600); Wp2T = [pwih@w0 | pwih@w1]
__global__ void k_fuse(const float* cwhhL, const float* pwihL,
                       const float* w0L, const float* w1L, float* Wc2T, float* Wp2T) {
  int z = blockIdx.z;
  const float* A  = (z < 2) ? cwhhL : pwihL;
  const float* Bm = (z & 1) ? w1L : w0L;
  float* C = ((z < 2) ? Wc2T : Wp2T) + (z & 1) * HID;
  gemm_body(A, HID, Bm, HID, false, nullptr, false, C, 600, 900, HID, HID);
}
__global__ void k_m2(const float* t1, const float* w, const float* b, float* t2) {
  gemm_body(t1, HID, w, HID, true, b, true, t2, HID, ROWS, HID, HID);
}

// mlp1: A is virtual concat [H0|H1|H2|H3|H4|inp] (1024 x 1600)
__global__ void k_mlp1(const float* __restrict__ Hcat, const float* __restrict__ inp,
                       const float* __restrict__ w, const float* __restrict__ bias,
                       float* __restrict__ out) {
  __shared__ __align__(16) float As[16][132];
  __shared__ __align__(16) float Bs[16][132];
  const int tid = threadIdx.x;
  const int tn = tid & 15, tm = tid >> 4;
  const int bn = blockIdx.x * 128, bm = blockIdx.y * 128;
  float acc[8][8]{};
  for (int k0 = 0; k0 < 1600; k0 += 16) {
    for (int idx = tid; idx < 2048; idx += 256) {
      int r = idx >> 4, kk = idx & 15;
      int gm = bm + r, gk = k0 + kk;
      float v;
      if (gk < 1500) { int seg = gk / 300; v = Hcat[seg*(ROWS*HID) + gm*HID + (gk - seg*300)]; }
      else            v = inp[gm*EMBD + (gk - 1500)];
      As[kk][r] = v;
    }
    for (int idx = tid; idx < 512; idx += 256) {
      int n = idx >> 2, kc = (idx & 3) * 4;
      int gn = bn + n, gk = k0 + kc;
      float4 v{};
      if (gn < HID) v = *(const float4*)(w + gn*1600 + gk);
      Bs[kc+0][n]=v.x; Bs[kc+1][n]=v.y; Bs[kc+2][n]=v.z; Bs[kc+3][n]=v.w;
    }
    __syncthreads();
#pragma unroll
    for (int kk = 0; kk < 16; ++kk) {
      float a8[8], b8[8];
      *(float4*)&a8[0] = *(const float4*)&As[kk][tm*8];
      *(float4*)&a8[4] = *(const float4*)&As[kk][tm*8+4];
      *(float4*)&b8[0] = *(const float4*)&Bs[kk][tn*8];
      *(float4*)&b8[4] = *(const float4*)&Bs[kk][tn*8+4];
#pragma unroll
      for (int i2 = 0; i2 < 8; ++i2)
#pragma unroll
        for (int j2 = 0; j2 < 8; ++j2) acc[i2][j2] += a8[i2]*b8[j2];
    }
    __syncthreads();
  }
#pragma unroll
  for (int i2 = 0; i2 < 8; ++i2) {
    int gm = bm + tm*8 + i2;
    if (gm >= ROWS) continue;
#pragma unroll
    for (int j2 = 0; j2 < 8; ++j2) {
      int gn = bn + tn*8 + j2;
      if (gn >= HID) continue;
      out[gm*HID + gn] = fmaxf(acc[i2][j2] + bias[gn], 0.f);
    }
  }
}

__global__ void k_mlp3(const float* __restrict__ t2, const float* __restrict__ w,
                       const float* __restrict__ b, float* __restrict__ out) {
  __shared__ float xs[32][HID];
  __shared__ float wsx[NCLS][HID];
  const int r0 = blockIdx.x * 32;
  for (int idx = threadIdx.x; idx < NCLS*HID; idx += 256) wsx[idx/HID][idx%HID] = w[idx];
  for (int idx = threadIdx.x; idx < 32*HID; idx += 256)
    xs[idx/HID][idx%HID] = t2[(r0 + idx/HID)*HID + idx%HID];
  __syncthreads();
  const int rl = threadIdx.x >> 3, o = threadIdx.x & 7;
  if (o < NCLS) {
    float acc = b[o];
    for (int k = 0; k < HID; ++k) acc += xs[rl][k]*wsx[o][k];
    out[(r0 + rl)*NCLS + o] = acc;
  }
}

// ---------------------------------------------------------------------------
// Sequential scan. 50 blocks x 512 threads; block g owns dims [g*6, g*6+6).
// Phase B thread unit: (dc2 in [0,21), ks in [0,12), bh in [0,2)) -> tid<504.
//   Each thread owns 2 weight columns (52 floats each) in VGPRs; loads are
//   UNCONDITIONAL (tail threads load a duplicate slice) so the compiler keeps
//   them register-resident.
// ---------------------------------------------------------------------------
__global__ __launch_bounds__(STH, 1)
void k_scan(const float* __restrict__ Hin, float* __restrict__ Hout,
            const float* __restrict__ giC, const float* __restrict__ ghP,
            const float* __restrict__ Wc2T, const float* __restrict__ Wp2T,
            const float* __restrict__ w0, const float* __restrict__ w1,
            const float* __restrict__ gatw,
            const float* __restrict__ cbhh, const float* __restrict__ pbih,
            const int* __restrict__ adj, const int* __restrict__ smask,
            float* __restrict__ dlog, float* __restrict__ mbuf,
            int* __restrict__ mflag, int* __restrict__ rflag)
{
  const int tid = threadIdx.x;
  const int bid = blockIdx.x;
  const int D0  = bid * ND;

  __shared__ float hist[BATCH][NSEQ][ND+1];
  __shared__ __align__(16) float uwl[BATCH][12][52];
  __shared__ __align__(16) float part[BATCH][42][16];   // 16-float rows: b128 reducer reads
  __shared__ float gate[BATCH][42];
  __shared__ float dlgl[BATCH][NSEQ];
  __shared__ float dred[BATCH][ND];

  for (int idx = tid; idx < BATCH*NSEQ*(ND+1); idx += STH) (&hist[0][0][0])[idx] = 0.f;
  for (int idx = tid; idx < BATCH*12*52;       idx += STH) (&uwl[0][0][0])[idx]  = 0.f;
  for (int idx = tid; idx < BATCH*42*16;       idx += STH) (&part[0][0][0])[idx] = 0.f;

  // ---- persistent per-thread setup -----------------------------------------
  const bool bact = (tid < 504);
  const int lt  = bact ? tid : 0;           // tail threads mirror thread 0
  const int dc2 = lt / 24, rr = lt % 24, ks = rr >> 1, bh = rr & 1;
  const int dl = dc2 / 7, cc = dc2 % 7;
  const int dcA = dl*7 + cc, dcB = (dl+3)*7 + cc;
  float wregA[52], wregB[52];
  {
    const int off = ks * 50;
#pragma unroll
    for (int t = 0; t < 2; ++t) {
      const int dim = D0 + dl + t*3;
      const float* src;
      if (cc < 3)      src = Wc2T + (cc*HID + dim)*600 + off;
      else if (cc < 6) src = Wp2T + ((cc-3)*HID + dim)*600 + off;
      else             src = (ks < 6) ? (w0 + dim*HID + off)
                                      : (w1 + dim*HID + off - HID);
      float* dst = t ? wregB : wregA;
#pragma unroll
      for (int q = 0; q < 50; ++q) dst[q] = src[q];
      dst[50] = 0.f; dst[51] = 0.f;
    }
  }
  const int rb = tid / 42, rdc = tid % 42;
  float rbias = 0.f;
  if (tid < 336) {
    const int rd = rdc / 7, rc = rdc % 7;
    if (rc < 3)      rbias = cbhh[rc*HID + D0 + rd];
    else if (rc < 6) rbias = pbih[(rc-3)*HID + D0 + rd];
  }
  float gw2 = 0.f;
  if (tid < BATCH*ND) gw2 = gatw[HID + D0 + (tid % ND)];

  __syncthreads();

  for (int i = 0; i < NSEQ; ++i) {
    // ---- hoisted loads (issue before any inter-block wait) -----------------
    float hx0=0,hx1=0,hx2=0,hx3=0,hx4=0,hx5=0,hx6=0;
    if (tid < BATCH*ND) {
      const int b = tid / ND, d = tid % ND, dim = D0 + d, row = b*NSEQ + i;
      const float* gi = giC + row*900;
      const float* gh = ghP + row*900;
      hx0 = gi[dim]; hx1 = gi[HID+dim]; hx2 = gi[2*HID+dim];
      hx3 = gh[dim]; hx4 = gh[HID+dim]; hx5 = gh[2*HID+dim];
      hx6 = Hin[row*HID + dim];
    }
    bool v1 = false, v2 = false; float sm1 = 0.f, sm2 = 0.f;
    if (i > 0) {
      const int b = tid >> 6, lane = tid & 63;
      const int* ar = adj   + (b*NSEQ + i)*NSEQ;
      const int* sr = smask + (b*NSEQ + i)*NSEQ;
      v1 = (lane < i)      && (ar[lane]      != 0);
      v2 = (lane + 64 < i) && (ar[lane + 64] != 0);
      sm1 = v1 ? (float)sr[lane]      : 0.f;
      sm2 = v2 ? (float)sr[lane + 64] : 0.f;
    }

    if (i > 0) {
      waitflags(rflag + (i-1)*64);
      if (tid < BATCH) dlgl[tid][i-1] = atom_ldf(dlog + tid*NSEQ + (i-1));
      __syncthreads();

      // ---- Phase A: masked softmax + m0/m1 slice (wave <-> batch) ----------
      {
        const int b = tid >> 6, lane = tid & 63;
        const float l1 = v1 ? dlgl[b][lane]      : -3.0e38f;
        const float l2 = v2 ? dlgl[b][lane + 64] : -3.0e38f;
        float mx = fmaxf(l1, l2);
#pragma unroll
        for (int off = 32; off; off >>= 1) mx = fmaxf(mx, __shfl_xor(mx, off));
        const float p1 = v1 ? expf(l1 - mx) : 0.f;
        const float p2 = v2 ? expf(l2 - mx) : 0.f;
        float ps = p1 + p2;
#pragma unroll
        for (int off = 32; off; off >>= 1) ps += __shfl_xor(ps, off);
        const float inv = 1.f / ps;     // i>=1 guarantees >=1 valid predecessor
        const float a1 = p1*inv, a2 = p2*inv;
        const float aS1 = a1*sm1, aD1 = a1 - aS1;
        const float aS2 = a2*sm2, aD2 = a2 - aS2;
        float s0[ND], s1v[ND];
#pragma unroll
        for (int d = 0; d < ND; ++d) {
          s0[d]  = aS1*hist[b][lane][d] + aS2*hist[b][lane+64][d];
          s1v[d] = aD1*hist[b][lane][d] + aD2*hist[b][lane+64][d];
        }
#pragma unroll
        for (int off = 32; off; off >>= 1) {
#pragma unroll
          for (int d = 0; d < ND; ++d) {
            s0[d]  += __shfl_xor(s0[d],  off);
            s1v[d] += __shfl_xor(s1v[d], off);
          }
        }
        if (lane == 0) {
#pragma unroll
          for (int d = 0; d < ND; ++d) {
            atom_stf(mbuf + b*600 +       D0 + d, s0[d]);
            atom_stf(mbuf + b*600 + HID + D0 + d, s1v[d]);
          }
        }
      }
      __syncthreads();   // vmcnt(0) drain: mbuf stores ack'd at LLC
      if (tid == 0) setflag(mflag + i*64 + bid);
      waitflags(mflag + i*64);
      for (int idx = tid; idx < BATCH*600; idx += STH) {
        const int b = idx / 600, k = idx % 600;
        uwl[b][k/50][k%50] = atom_ldf(mbuf + idx);
      }
    }
    __syncthreads();

    // ---- Phase B: fused GEMV partials, 2 columns per thread ----------------
    if (bact) {
#pragma unroll
      for (int j = 0; j < 4; ++j) {
        const int b = bh*4 + j;
        const float4* u4 = (const float4*)(&uwl[b][ks][0]);
        float accA = 0.f, accB = 0.f;
#pragma unroll
        for (int q = 0; q < 13; ++q) {
          const float4 u = u4[q];
          accA += u.x*wregA[4*q+0] + u.y*wregA[4*q+1] + u.z*wregA[4*q+2] + u.w*wregA[4*q+3];
          accB += u.x*wregB[4*q+0] + u.y*wregB[4*q+1] + u.z*wregB[4*q+2] + u.w*wregB[4*q+3];
        }
        part[b][dcA][ks] = accA;
        part[b][dcB][ks] = accB;
      }
    }
    __syncthreads();
    if (tid < 336) {
      const float4* p4 = (const float4*)(&part[rb][rdc][0]);
      const float4 q0 = p4[0], q1 = p4[1], q2 = p4[2];
      gate[rb][rdc] = rbias + ((q0.x+q0.y)+(q0.z+q0.w))
                            + ((q1.x+q1.y)+(q1.z+q1.w))
                            + ((q2.x+q2.y)+(q2.z+q2.w));
    }
    __syncthreads();

    // ---- Phase C: GRU elementwise + writeback ------------------------------
    if (tid < BATCH*ND) {
      const int b = tid / ND, d = tid % ND;
      const int dim = D0 + d, row = b*NSEQ + i;
      const float ghc_r = gate[b][d*7+0], ghc_z = gate[b][d*7+1], ghc_n = gate[b][d*7+2];
      const float gip_r = gate[b][d*7+3], gip_z = gate[b][d*7+4], gip_n = gate[b][d*7+5];
      const float Mv    = gate[b][d*7+6];             // == 0 exactly at i==0
      // C = grus_c(x, M)
      const float r  = sigm(hx0 + ghc_r);
      const float z  = sigm(hx1 + ghc_z);
      const float n  = tanhf(hx2 + r*ghc_n);
      const float Cv = (1.f - z)*n + z*Mv;
      // P = grus_p(M, x)
      const float rp = sigm(gip_r + hx3);
      const float zp = sigm(gip_z + hx4);
      const float np = tanhf(gip_n + rp*hx5);
      const float Pv = (1.f - zp)*np + zp*hx6;
      const float ov = Cv + Pv;
      Hout[row*HID + dim] = ov;
      hist[b][i][d] = ov;
      dred[b][d] = ov * gw2;
    }
    __syncthreads();
    if (tid < BATCH) {
      float s = 0.f;
#pragma unroll
      for (int d = 0; d < ND; ++d) s += dred[tid][d];
      atomicAdd(dlog + tid*NSEQ + i, s);
    }
    __syncthreads();   // vmcnt(0) drain: dlog adds ack'd at LLC
    if (tid == 0) setflag(rflag + i*64 + bid);
  }
}

// ---------------------------------------------------------------------------
extern "C" void kernel_launch(void* const* d_in, const int* in_sizes, int n_in,
                              void* d_out, int out_size, void* d_ws, size_t ws_size,
                              hipStream_t stream) {
  const float* inp   = (const float*)d_in[0];
  const int*   adj   = (const int*)d_in[1];
  const int*   smask = (const int*)d_in[2];
  // d_in[3] text_length: unused by the reference forward
  const float* fc1w = (const float*)d_in[4];
  const float* fc1b = (const float*)d_in[5];
  const float* gatw = (const float*)d_in[6];
  // d_in[7] gat_b: cancels in softmax
  const float* wr0  = (const float*)d_in[8];
  const float* wr1  = (const float*)d_in[9];
  const float* cwih = (const float*)d_in[10];
  const float* cwhh = (const float*)d_in[11];
  const float* cbih = (const float*)d_in[12];
  const float* cbhh = (const float*)d_in[13];
  const float* pwih = (const float*)d_in[14];
  const float* pwhh = (const float*)d_in[15];
  const float* pbih = (const float*)d_in[16];
  const float* pbhh = (const float*)d_in[17];
  const float* m1w  = (const float*)d_in[18];
  const float* m1b  = (const float*)d_in[19];
  const float* m2w  = (const float*)d_in[20];
  const float* m2b  = (const float*)d_in[21];
  const float* m3w  = (const float*)d_in[22];
  const float* m3b  = (const float*)d_in[23];
  float* out = (float*)d_out;

  float* ws    = (float*)d_ws;
  float* H     = ws + WS_H;
  float* giC   = ws + WS_GIC;
  float* ghP   = ws + WS_GHP;
  float* Wc2T  = ws + WS_WC2;
  float* Wp2T  = ws + WS_WP2;
  float* mbuf  = ws + WS_MBUF;
  float* dlog  = ws + WS_DLOG;
  int*   mflag = (int*)(ws + WS_MF);
  int*   rflag = (int*)(ws + WS_RF);

  // zero dlog (4096 f) + mflag/rflag (2*32768 ints), contiguous: 278528 bytes
  hipMemsetAsync(dlog, 0, (size_t)(NLAY*BATCH*NSEQ)*4 + 2u*NLAY*NSEQ*64*4, stream);

  k_fc1<<<dim3(3, 8, 1), 256, 0, stream>>>(inp, fc1w, fc1b, H);

  for (int l = 0; l < NLAY; ++l) {
    float* Hin  = H + l*(ROWS*HID);
    float* Hout = H + (l+1)*(ROWS*HID);
    k_fuse<<<dim3(3, 8, 4), 256, 0, stream>>>(cwhh + l*900*HID, pwih + l*900*HID,
                                              wr0 + l*HID*HID, wr1 + l*HID*HID, Wc2T, Wp2T);
    k_prep<<<dim3(8, 8, 2), 256, 0, stream>>>(Hin, cwih + l*900*HID, cbih + l*900,
                                              pwhh + l*900*HID, pbhh + l*900, giC, ghP);
    k_scan<<<GS, STH, 0, stream>>>(Hin, Hout, giC, ghP, Wc2T, Wp2T,
                                   wr0 + l*HID*HID, wr1 + l*HID*HID, gatw + l*2*HID,
                                   cbhh + l*900, pbih + l*900,
                                   adj, smask, dlog + l*BATCH*NSEQ, mbuf,
                                   mflag + l*NSEQ*64, rflag + l*NSEQ*64);
  }

  float* t1 = giC;  // reuse
  float* t2 = ghP;
  k_mlp1<<<dim3(3, 8, 1), 256, 0, stream>>>(H, inp, m1w, m1b, t1);
  k_m2  <<<dim3(3, 8, 1), 256, 0, stream>>>(t1, m2w, m2b, t2);
  k_mlp3<<<32, 256, 0, stream>>>(t2, m3w, m3b, out);
}